// Round 2
// baseline (401.346 us; speedup 1.0000x reference)
//
#include <hip/hip_runtime.h>
#include <hip/hip_bf16.h>
#include <stdint.h>

#define B_ 8
#define C_ 1024
#define D_ 128
#define L_ 2048

typedef __attribute__((ext_vector_type(8))) short short8;
typedef __attribute__((ext_vector_type(4))) float floatx4;

// async global->LDS direct copy, 16 bytes per lane
#define GLDS16(g, l)                                                          \
    __builtin_amdgcn_global_load_lds(                                         \
        (const __attribute__((address_space(1))) uint32_t*)(g),               \
        (__attribute__((address_space(3))) uint32_t*)(l), 16, 0, 0)

__device__ inline float b2f(uint16_t u) {
    union { uint32_t i; float f; } x; x.i = (uint32_t)u << 16; return x.f;
}
__device__ inline uint16_t f2b(float f) {
    union { uint32_t i; float f; } x; x.f = f;
    uint32_t r = (x.i + 0x7fff + ((x.i >> 16) & 1)) >> 16;
    return (uint16_t)r;
}

// ---------------- small cast kernel: f32 -> bf16 ----------------
__global__ void cast_f32_bf16(const float* __restrict__ src, uint16_t* __restrict__ dst, int n) {
    int i = blockIdx.x * 256 + threadIdx.x;
    if (i < n) dst[i] = f2b(src[i]);
}

// ---------------- transpose + cast: x [B][C][L] f32 -> xT [B][L][C] bf16 ----------------
__global__ __launch_bounds__(256) void transpose_cast(const float* __restrict__ x, uint16_t* __restrict__ xT) {
    __shared__ float tile[32][33];
    int b = blockIdx.z;
    int l0 = blockIdx.x * 32, c0 = blockIdx.y * 32;
    int tx = threadIdx.x, ty = threadIdx.y;  // blockDim (32, 8)
    const float* xb = x + (size_t)b * C_ * L_;
#pragma unroll
    for (int i = 0; i < 4; i++)
        tile[ty + i * 8][tx] = xb[(size_t)(c0 + ty + i * 8) * L_ + l0 + tx];
    __syncthreads();
    uint16_t* xtb = xT + (size_t)b * L_ * C_;
#pragma unroll
    for (int i = 0; i < 4; i++) {
        int l = l0 + ty + i * 8, c = c0 + tx;
        xtb[(size_t)l * C_ + c] = f2b(tile[tx][ty + i * 8]);
    }
}

// ---------------- generic NT GEMM: C[m][n] = sum_k A[m][k]*B[n][k] (bf16 in, f32 acc) ----
// EPI 0: bf16 store C[m*ldc+n] + bias[m]
// EPI 1: bf16 store C[n*ldc+m] + bias[m]   (transposed store, for q/k)
// EPI 2: bf16 store C[m*ldc+n]             (energy)
// EPI 3: f32  store C[m*ldc+n] = gamma*acc + X[same idx]  (final output)
template <int EPI>
__global__ __launch_bounds__(256) void gemm_nt(
    const uint16_t* __restrict__ A, const uint16_t* __restrict__ B,
    long sA, long sB, const float* __restrict__ bias,
    void* __restrict__ Cout, long sC, int ldc,
    int N, int K, const float* __restrict__ gamma, const float* __restrict__ X) {

    __shared__ uint4 As4[512];  // 128 rows x 32 cols bf16, row-major (64B rows)
    __shared__ uint4 Bs4[512];
    uint16_t* As = (uint16_t*)As4;
    uint16_t* Bs = (uint16_t*)Bs4;

    const int b = blockIdx.z;
    const uint16_t* Ab = A + (size_t)b * sA;
    const uint16_t* Bb = B + (size_t)b * sB;
    const int m0 = blockIdx.y * 128;
    const int n0 = blockIdx.x * 128;

    const int t = threadIdx.x;
    const int lane = t & 63;
    const int wave = t >> 6;
    const int wm = (wave >> 1) * 64;
    const int wn = (wave & 1) * 64;

    floatx4 acc[4][4] = {};

    // staging slot assignment: thread t owns 16B slots t and t+256 of each tile
    // (within a wave: lds addr = wave_base + lane*16 — exactly global_load_lds's
    //  required linear layout)
    const int c0 = t, c1 = t + 256;
    const uint16_t* gA0 = Ab + (size_t)(m0 + (c0 >> 2)) * K + (c0 & 3) * 8;
    const uint16_t* gA1 = Ab + (size_t)(m0 + (c1 >> 2)) * K + (c1 & 3) * 8;
    const uint16_t* gB0 = Bb + (size_t)(n0 + (c0 >> 2)) * K + (c0 & 3) * 8;
    const uint16_t* gB1 = Bb + (size_t)(n0 + (c1 >> 2)) * K + (c1 & 3) * 8;

    for (int k0 = 0; k0 < K; k0 += 32) {
        __syncthreads();  // previous iteration's LDS reads done
        GLDS16(gA0 + k0, &As4[c0]);
        GLDS16(gA1 + k0, &As4[c1]);
        GLDS16(gB0 + k0, &Bs4[c0]);
        GLDS16(gB1 + k0, &Bs4[c1]);
        __syncthreads();  // vmcnt(0) drained -> tile staged

        const int kg = (lane >> 4) * 8;  // halfword offset of this lane's k-group
        const int rA = wm + (lane & 15);
        const int rB = wn + (lane & 15);
        short8 af[4], bf[4];
#pragma unroll
        for (int i = 0; i < 4; i++) af[i] = *(const short8*)(As + (rA + i * 16) * 32 + kg);
#pragma unroll
        for (int j = 0; j < 4; j++) bf[j] = *(const short8*)(Bs + (rB + j * 16) * 32 + kg);
#pragma unroll
        for (int i = 0; i < 4; i++)
#pragma unroll
            for (int j = 0; j < 4; j++)
                acc[i][j] = __builtin_amdgcn_mfma_f32_16x16x32_bf16(af[i], bf[j], acc[i][j], 0, 0, 0);
    }

    // ---------------- epilogue ----------------
    if (EPI == 0 || EPI == 1 || EPI == 2) {
        uint16_t* Cb = (uint16_t*)Cout + (size_t)b * sC;
#pragma unroll
        for (int i = 0; i < 4; i++) {
#pragma unroll
            for (int j = 0; j < 4; j++) {
                int mrow = m0 + wm + i * 16 + ((lane >> 4) << 2);
                int ncol = n0 + wn + j * 16 + (lane & 15);
#pragma unroll
                for (int r = 0; r < 4; r++) {
                    float val = acc[i][j][r];
                    if (EPI == 0 || EPI == 1) val += bias[mrow + r];
                    if (EPI == 1)
                        Cb[(size_t)ncol * ldc + mrow + r] = f2b(val);
                    else
                        Cb[(size_t)(mrow + r) * ldc + ncol] = f2b(val);
                }
            }
        }
    } else {  // EPI == 3
        float g = gamma[0];
        float* Ob = (float*)Cout + (size_t)b * sC;
        const float* Xb = X + (size_t)b * sC;
#pragma unroll
        for (int i = 0; i < 4; i++) {
#pragma unroll
            for (int j = 0; j < 4; j++) {
                int mrow = m0 + wm + i * 16 + ((lane >> 4) << 2);
                int ncol = n0 + wn + j * 16 + (lane & 15);
#pragma unroll
                for (int r = 0; r < 4; r++) {
                    size_t idx = (size_t)(mrow + r) * ldc + ncol;
                    Ob[idx] = g * acc[i][j][r] + Xb[idx];
                }
            }
        }
    }
}

// ---------------- row softmax, in-place bf16, one block per row ----------------
__global__ __launch_bounds__(256) void softmax_rows(uint16_t* __restrict__ att) {
    const int i = blockIdx.x, b = blockIdx.y;
    uint16_t* row = att + ((size_t)b * L_ + i) * L_;
    const int t = threadIdx.x;
    short8 v = *(const short8*)(row + t * 8);
    float f[8];
    float m = -1e30f;
#pragma unroll
    for (int e = 0; e < 8; e++) { f[e] = b2f((uint16_t)v[e]); m = fmaxf(m, f[e]); }
#pragma unroll
    for (int off = 32; off >= 1; off >>= 1) m = fmaxf(m, __shfl_xor(m, off));
    __shared__ float redm[4], reds[4];
    const int wave = t >> 6;
    if ((t & 63) == 0) redm[wave] = m;
    __syncthreads();
    m = fmaxf(fmaxf(redm[0], redm[1]), fmaxf(redm[2], redm[3]));
    float s = 0.f;
#pragma unroll
    for (int e = 0; e < 8; e++) { f[e] = __expf(f[e] - m); s += f[e]; }
#pragma unroll
    for (int off = 32; off >= 1; off >>= 1) s += __shfl_xor(s, off);
    if ((t & 63) == 0) reds[wave] = s;
    __syncthreads();
    s = reds[0] + reds[1] + reds[2] + reds[3];
    float inv = 1.0f / s;
    short8 o;
#pragma unroll
    for (int e = 0; e < 8; e++) o[e] = (short)f2b(f[e] * inv);
    *(short8*)(row + t * 8) = o;
}

// ---------------- workspace layout (bytes) ----------------
#define OFF_XT   0ull
#define OFF_Q    33554432ull
#define OFF_K    37748736ull
#define OFF_V    41943040ull
#define OFF_ATT  75497472ull
#define OFF_WQ   142606336ull
#define OFF_WK   142868480ull
#define OFF_WV   143130624ull
// total 145227776 bytes (~139 MB)

extern "C" void kernel_launch(void* const* d_in, const int* in_sizes, int n_in,
                              void* d_out, int out_size, void* d_ws, size_t ws_size,
                              hipStream_t stream) {
    const float* x  = (const float*)d_in[0];
    const float* Wq = (const float*)d_in[1];
    const float* bq = (const float*)d_in[2];
    const float* Wk = (const float*)d_in[3];
    const float* bk = (const float*)d_in[4];
    const float* Wv = (const float*)d_in[5];
    const float* bv = (const float*)d_in[6];
    const float* gamma = (const float*)d_in[7];
    float* out = (float*)d_out;
    char* ws = (char*)d_ws;

    uint16_t* xT   = (uint16_t*)(ws + OFF_XT);
    uint16_t* q    = (uint16_t*)(ws + OFF_Q);
    uint16_t* k    = (uint16_t*)(ws + OFF_K);
    uint16_t* v    = (uint16_t*)(ws + OFF_V);
    uint16_t* att  = (uint16_t*)(ws + OFF_ATT);
    uint16_t* Wqb  = (uint16_t*)(ws + OFF_WQ);
    uint16_t* Wkb  = (uint16_t*)(ws + OFF_WK);
    uint16_t* Wvb  = (uint16_t*)(ws + OFF_WV);

    // 1. weight casts
    cast_f32_bf16<<<dim3((D_ * C_ + 255) / 256), 256, 0, stream>>>(Wq, Wqb, D_ * C_);
    cast_f32_bf16<<<dim3((D_ * C_ + 255) / 256), 256, 0, stream>>>(Wk, Wkb, D_ * C_);
    cast_f32_bf16<<<dim3((C_ * C_ + 255) / 256), 256, 0, stream>>>(Wv, Wvb, C_ * C_);

    // 2. x transpose+cast: [B][C][L] f32 -> [B][L][C] bf16
    transpose_cast<<<dim3(L_ / 32, C_ / 32, B_), dim3(32, 8), 0, stream>>>(x, xT);

    // 3. q = Wq*x (+bq), stored transposed [B][L][D]; same for k
    gemm_nt<1><<<dim3(L_ / 128, 1, B_), 256, 0, stream>>>(
        Wqb, xT, 0, (long)L_ * C_, bq, q, (long)L_ * D_, D_, L_, C_, nullptr, nullptr);
    gemm_nt<1><<<dim3(L_ / 128, 1, B_), 256, 0, stream>>>(
        Wkb, xT, 0, (long)L_ * C_, bk, k, (long)L_ * D_, D_, L_, C_, nullptr, nullptr);
    // v = Wv*x (+bv), stored [B][C][L]
    gemm_nt<0><<<dim3(L_ / 128, C_ / 128, B_), 256, 0, stream>>>(
        Wvb, xT, 0, (long)L_ * C_, bv, v, (long)C_ * L_, L_, L_, C_, nullptr, nullptr);

    // 4. energy[b][i][j] = sum_d q[b][i][d]*k[b][j][d] -> bf16 att
    gemm_nt<2><<<dim3(L_ / 128, L_ / 128, B_), 256, 0, stream>>>(
        q, k, (long)L_ * D_, (long)L_ * D_, nullptr, att, (long)L_ * L_, L_, L_, D_, nullptr, nullptr);

    // 5. softmax rows, in place
    softmax_rows<<<dim3(L_, B_), 256, 0, stream>>>(att);

    // 6. out[b][c][i] = gamma * sum_j v[b][c][j]*att[b][i][j] + x[b][c][i]
    gemm_nt<3><<<dim3(L_ / 128, C_ / 128, B_), 256, 0, stream>>>(
        v, att, (long)C_ * L_, (long)L_ * L_, nullptr, out, (long)C_ * L_, L_, L_, L_, gamma, x);
}

// Round 3
// 355.392 us; speedup vs baseline: 1.1293x; 1.1293x over previous
//
#include <hip/hip_runtime.h>
#include <hip/hip_bf16.h>
#include <stdint.h>

#define B_ 8
#define C_ 1024
#define D_ 128
#define L_ 2048

typedef __attribute__((ext_vector_type(8))) short short8;
typedef __attribute__((ext_vector_type(4))) float floatx4;

// async global->LDS direct copy, 16 bytes per lane
#define GLDS16(g, l)                                                          \
    __builtin_amdgcn_global_load_lds(                                         \
        (const __attribute__((address_space(1))) uint32_t*)(g),               \
        (__attribute__((address_space(3))) uint32_t*)(l), 16, 0, 0)

__device__ inline float b2f(uint16_t u) {
    union { uint32_t i; float f; } x; x.i = (uint32_t)u << 16; return x.f;
}
__device__ inline uint16_t f2b(float f) {
    union { uint32_t i; float f; } x; x.f = f;
    uint32_t r = (x.i + 0x7fff + ((x.i >> 16) & 1)) >> 16;
    return (uint16_t)r;
}

// ---------------- small cast kernel: f32 -> bf16 ----------------
__global__ void cast_f32_bf16(const float* __restrict__ src, uint16_t* __restrict__ dst, int n) {
    int i = blockIdx.x * 256 + threadIdx.x;
    if (i < n) dst[i] = f2b(src[i]);
}

// ---------------- transpose + cast: x [B][C][L] f32 -> xT [B][L][C] bf16 ----------------
__global__ __launch_bounds__(256) void transpose_cast(const float* __restrict__ x, uint16_t* __restrict__ xT) {
    __shared__ float tile[32][33];
    int b = blockIdx.z;
    int l0 = blockIdx.x * 32, c0 = blockIdx.y * 32;
    int tx = threadIdx.x, ty = threadIdx.y;  // blockDim (32, 8)
    const float* xb = x + (size_t)b * C_ * L_;
#pragma unroll
    for (int i = 0; i < 4; i++)
        tile[ty + i * 8][tx] = xb[(size_t)(c0 + ty + i * 8) * L_ + l0 + tx];
    __syncthreads();
    uint16_t* xtb = xT + (size_t)b * L_ * C_;
#pragma unroll
    for (int i = 0; i < 4; i++) {
        int l = l0 + ty + i * 8, c = c0 + tx;
        xtb[(size_t)l * C_ + c] = f2b(tile[tx][ty + i * 8]);
    }
}

// ---------------- qk GEMM (128^2 tile, round-2-validated structure) ----------------
// A = Wqk [256][K] stacked (rows 0-127 Wq, 128-255 Wk), B = xT [L][K] (batched)
// out: qk[b][l][256] = [q(l,0:128) | k(l,0:128)] bf16, bias bq/bk added
__global__ __launch_bounds__(256) void gemm_qk(
    const uint16_t* __restrict__ A, const uint16_t* __restrict__ B, long sB,
    const float* __restrict__ bq, const float* __restrict__ bk,
    uint16_t* __restrict__ Cout, long sC, int K) {

    __shared__ uint4 As4[512];  // 128 x 32 bf16
    __shared__ uint4 Bs4[512];
    uint16_t* As = (uint16_t*)As4;
    uint16_t* Bs = (uint16_t*)Bs4;

    const int b = blockIdx.z;
    const uint16_t* Ab = A;
    const uint16_t* Bb = B + (size_t)b * sB;
    const int m0 = blockIdx.y * 128;
    const int n0 = blockIdx.x * 128;

    const int t = threadIdx.x;
    const int lane = t & 63;
    const int wave = t >> 6;
    const int wm = (wave >> 1) * 64;
    const int wn = (wave & 1) * 64;

    floatx4 acc[4][4] = {};

    const int c0 = t, c1 = t + 256;
    const uint16_t* gA0 = Ab + (size_t)(m0 + (c0 >> 2)) * K + (c0 & 3) * 8;
    const uint16_t* gA1 = Ab + (size_t)(m0 + (c1 >> 2)) * K + (c1 & 3) * 8;
    const uint16_t* gB0 = Bb + (size_t)(n0 + (c0 >> 2)) * K + (c0 & 3) * 8;
    const uint16_t* gB1 = Bb + (size_t)(n0 + (c1 >> 2)) * K + (c1 & 3) * 8;

    for (int k0 = 0; k0 < K; k0 += 32) {
        __syncthreads();
        GLDS16(gA0 + k0, &As4[c0]);
        GLDS16(gA1 + k0, &As4[c1]);
        GLDS16(gB0 + k0, &Bs4[c0]);
        GLDS16(gB1 + k0, &Bs4[c1]);
        __syncthreads();

        const int kg = (lane >> 4) * 8;
        const int rA = wm + (lane & 15);
        const int rB = wn + (lane & 15);
        short8 af[4], bf[4];
#pragma unroll
        for (int i = 0; i < 4; i++) af[i] = *(const short8*)(As + (rA + i * 16) * 32 + kg);
#pragma unroll
        for (int j = 0; j < 4; j++) bf[j] = *(const short8*)(Bs + (rB + j * 16) * 32 + kg);
#pragma unroll
        for (int i = 0; i < 4; i++)
#pragma unroll
            for (int j = 0; j < 4; j++)
                acc[i][j] = __builtin_amdgcn_mfma_f32_16x16x32_bf16(af[i], bf[j], acc[i][j], 0, 0, 0);
    }

    uint16_t* Cb = Cout + (size_t)b * sC;
#pragma unroll
    for (int i = 0; i < 4; i++)
#pragma unroll
        for (int j = 0; j < 4; j++) {
            int mrow = m0 + wm + i * 16 + ((lane >> 4) << 2);
            int ncol = n0 + wn + j * 16 + (lane & 15);
#pragma unroll
            for (int r = 0; r < 4; r++) {
                int mr = mrow + r;
                float val = acc[i][j][r] + (mr < 128 ? bq[mr] : bk[mr - 128]);
                Cb[(size_t)ncol * 256 + mr] = f2b(val);  // transposed store into [L][256]
            }
        }
}

// ---------------- 256^2 tile, BK=64, 8-wave, 2-phase prefetch GEMM ----------------
// C[m][n] = sum_k A[m][k]*B[n][k], bf16 in, f32 acc.
// EPI 0: bf16 store + bias[m]; EPI 2: bf16 store; EPI 3: f32 gamma*acc + X
template <int EPI>
__global__ __launch_bounds__(512, 2) void gemm256(
    const uint16_t* __restrict__ A, const uint16_t* __restrict__ B,
    int lda, int ldb, long sA, long sB, const float* __restrict__ bias,
    void* __restrict__ Cout, long sC, int ldc, int K,
    const float* __restrict__ gamma, const float* __restrict__ X) {

    __shared__ uint4 As4[2][2048];  // [buf][256 rows x 4 chunks]  32 KB each
    __shared__ uint4 Bs4[2][2048];

    const int b = blockIdx.z;
    const uint16_t* Ab = A + (size_t)b * sA;
    const uint16_t* Bb = B + (size_t)b * sB;
    const int m0 = blockIdx.y * 256;
    const int n0 = blockIdx.x * 256;

    const int t = threadIdx.x;          // 512 threads = 8 waves
    const int lane = t & 63;
    const int wid = t >> 6;
    const int wm = (wid >> 2) * 128;    // 2 M-waves
    const int wn = (wid & 3) * 64;      // 4 N-waves

    // staging map: slot s = t + 512*r, row = s>>3, chunk = s&7 (16B chunks, 8/row)
    const int srow = t >> 3;
    const int schunk = (t & 7) * 8;     // halfword offset in row
    const uint16_t* gA = Ab + (size_t)(m0 + srow) * lda + schunk;
    const uint16_t* gB = Bb + (size_t)(n0 + srow) * ldb + schunk;

    floatx4 acc[8][4] = {};
    const int nt = K >> 6;

#define STAGE256(p, k0)                                                      \
    {                                                                        \
        _Pragma("unroll") for (int r = 0; r < 4; r++) {                      \
            GLDS16(gA + (size_t)(64 * r) * lda + (k0), &As4[p][t + 512 * r]);\
            GLDS16(gB + (size_t)(64 * r) * ldb + (k0), &Bs4[p][t + 512 * r]);\
        }                                                                    \
    }

    STAGE256(0, 0);
    __syncthreads();  // drains vmcnt(0): buf0 staged

    for (int kt = 0; kt < nt; kt++) {
        const int cur = kt & 1;
        if (kt + 1 < nt) STAGE256(cur ^ 1, (kt + 1) * 64);  // prefetch overlaps compute

        const uint16_t* Ac = (const uint16_t*)As4[cur];
        const uint16_t* Bc = (const uint16_t*)Bs4[cur];
        const int ra = (wm + (lane & 15)) * 64 + (lane >> 4) * 8;
        const int rb = (wn + (lane & 15)) * 64 + (lane >> 4) * 8;
#pragma unroll
        for (int ks = 0; ks < 2; ks++) {
            short8 af[8], bf[4];
#pragma unroll
            for (int mi = 0; mi < 8; mi++) af[mi] = *(const short8*)(Ac + ra + mi * (16 * 64) + ks * 32);
#pragma unroll
            for (int nj = 0; nj < 4; nj++) bf[nj] = *(const short8*)(Bc + rb + nj * (16 * 64) + ks * 32);
#pragma unroll
            for (int mi = 0; mi < 8; mi++)
#pragma unroll
                for (int nj = 0; nj < 4; nj++)
                    acc[mi][nj] = __builtin_amdgcn_mfma_f32_16x16x32_bf16(af[mi], bf[nj], acc[mi][nj], 0, 0, 0);
        }
        __syncthreads();  // drains vmcnt(0) for prefetched tile; LDS reads done
    }
#undef STAGE256

    if (EPI == 0 || EPI == 2) {
        uint16_t* Cb = (uint16_t*)Cout + (size_t)b * sC;
#pragma unroll
        for (int mi = 0; mi < 8; mi++)
#pragma unroll
            for (int nj = 0; nj < 4; nj++) {
                int mrow = m0 + wm + mi * 16 + ((lane >> 4) << 2);
                int ncol = n0 + wn + nj * 16 + (lane & 15);
#pragma unroll
                for (int r = 0; r < 4; r++) {
                    float val = acc[mi][nj][r];
                    if (EPI == 0) val += bias[mrow + r];
                    Cb[(size_t)(mrow + r) * ldc + ncol] = f2b(val);
                }
            }
    } else {  // EPI == 3
        float g = gamma[0];
        float* Ob = (float*)Cout + (size_t)b * sC;
        const float* Xb = X + (size_t)b * sC;
#pragma unroll
        for (int mi = 0; mi < 8; mi++)
#pragma unroll
            for (int nj = 0; nj < 4; nj++) {
                int mrow = m0 + wm + mi * 16 + ((lane >> 4) << 2);
                int ncol = n0 + wn + nj * 16 + (lane & 15);
#pragma unroll
                for (int r = 0; r < 4; r++) {
                    size_t idx = (size_t)(mrow + r) * ldc + ncol;
                    Ob[idx] = g * acc[mi][nj][r] + Xb[idx];
                }
            }
    }
}

// ---------------- row softmax, in-place bf16, one block per row ----------------
__global__ __launch_bounds__(256) void softmax_rows(uint16_t* __restrict__ att) {
    const int i = blockIdx.x, b = blockIdx.y;
    uint16_t* row = att + ((size_t)b * L_ + i) * L_;
    const int t = threadIdx.x;
    short8 v = *(const short8*)(row + t * 8);
    float f[8];
    float m = -1e30f;
#pragma unroll
    for (int e = 0; e < 8; e++) { f[e] = b2f((uint16_t)v[e]); m = fmaxf(m, f[e]); }
#pragma unroll
    for (int off = 32; off >= 1; off >>= 1) m = fmaxf(m, __shfl_xor(m, off));
    __shared__ float redm[4], reds[4];
    const int wave = t >> 6;
    if ((t & 63) == 0) redm[wave] = m;
    __syncthreads();
    m = fmaxf(fmaxf(redm[0], redm[1]), fmaxf(redm[2], redm[3]));
    float s = 0.f;
#pragma unroll
    for (int e = 0; e < 8; e++) { f[e] = __expf(f[e] - m); s += f[e]; }
#pragma unroll
    for (int off = 32; off >= 1; off >>= 1) s += __shfl_xor(s, off);
    if ((t & 63) == 0) reds[wave] = s;
    __syncthreads();
    s = reds[0] + reds[1] + reds[2] + reds[3];
    float inv = 1.0f / s;
    short8 o;
#pragma unroll
    for (int e = 0; e < 8; e++) o[e] = (short)f2b(f[e] * inv);
    *(short8*)(row + t * 8) = o;
}

// ---------------- workspace layout (bytes), total 145,227,776 ----------------
#define OFF_XT   0ull           // 33,554,432  xT  [B][L][C] bf16
#define OFF_QK   33554432ull    //  8,388,608  qk  [B][L][256] bf16
#define OFF_V    41943040ull    // 33,554,432  v   [B][C][L] bf16
#define OFF_ATT  75497472ull    // 67,108,864  att [B][L][L] bf16
#define OFF_WQK  142606336ull   //    524,288  Wqk [256][1024] bf16
#define OFF_WV   143130624ull   //  2,097,152  Wv  [1024][1024] bf16

extern "C" void kernel_launch(void* const* d_in, const int* in_sizes, int n_in,
                              void* d_out, int out_size, void* d_ws, size_t ws_size,
                              hipStream_t stream) {
    const float* x  = (const float*)d_in[0];
    const float* Wq = (const float*)d_in[1];
    const float* bq = (const float*)d_in[2];
    const float* Wk = (const float*)d_in[3];
    const float* bk = (const float*)d_in[4];
    const float* Wv = (const float*)d_in[5];
    const float* bv = (const float*)d_in[6];
    const float* gamma = (const float*)d_in[7];
    float* out = (float*)d_out;
    char* ws = (char*)d_ws;

    uint16_t* xT   = (uint16_t*)(ws + OFF_XT);
    uint16_t* qk   = (uint16_t*)(ws + OFF_QK);
    uint16_t* v    = (uint16_t*)(ws + OFF_V);
    uint16_t* att  = (uint16_t*)(ws + OFF_ATT);
    uint16_t* Wqkb = (uint16_t*)(ws + OFF_WQK);
    uint16_t* Wvb  = (uint16_t*)(ws + OFF_WV);

    // 1. weight casts (Wq into rows 0-127, Wk into rows 128-255 of Wqk)
    cast_f32_bf16<<<dim3((D_ * C_ + 255) / 256), 256, 0, stream>>>(Wq, Wqkb, D_ * C_);
    cast_f32_bf16<<<dim3((D_ * C_ + 255) / 256), 256, 0, stream>>>(Wk, Wqkb + D_ * C_, D_ * C_);
    cast_f32_bf16<<<dim3((C_ * C_ + 255) / 256), 256, 0, stream>>>(Wv, Wvb, C_ * C_);

    // 2. x transpose+cast: [B][C][L] f32 -> [B][L][C] bf16
    transpose_cast<<<dim3(L_ / 32, C_ / 32, B_), dim3(32, 8), 0, stream>>>(x, xT);

    // 3. q,k in one dispatch: qk[b][l][0:128]=q, [128:256]=k (transposed store)
    gemm_qk<<<dim3(L_ / 128, 2, B_), 256, 0, stream>>>(
        Wqkb, xT, (long)L_ * C_, bq, bk, qk, (long)L_ * 256, C_);

    // 4. v = Wv*x (+bv), stored [B][C][L]
    gemm256<0><<<dim3(L_ / 256, C_ / 256, B_), 512, 0, stream>>>(
        Wvb, xT, C_, C_, 0, (long)L_ * C_, bv, v, (long)C_ * L_, L_, C_, nullptr, nullptr);

    // 5. energy[b][i][j] = sum_d q[b][i][d]*k[b][j][d] -> bf16 att
    gemm256<2><<<dim3(L_ / 256, L_ / 256, B_), 512, 0, stream>>>(
        qk, qk + 128, 256, 256, (long)L_ * 256, (long)L_ * 256, nullptr,
        att, (long)L_ * L_, L_, D_, nullptr, nullptr);

    // 6. softmax rows, in place
    softmax_rows<<<dim3(L_, B_), 256, 0, stream>>>(att);

    // 7. out[b][c][i] = gamma * sum_j v[b][c][j]*att[b][i][j] + x[b][c][i]
    gemm256<3><<<dim3(L_ / 256, C_ / 256, B_), 512, 0, stream>>>(
        v, att, L_, L_, (long)C_ * L_, (long)L_ * L_, nullptr,
        out, (long)C_ * L_, L_, L_, gamma, x);
}

// Round 4
// 341.774 us; speedup vs baseline: 1.1743x; 1.0398x over previous
//
#include <hip/hip_runtime.h>
#include <hip/hip_bf16.h>
#include <stdint.h>

#define B_ 8
#define C_ 1024
#define D_ 128
#define L_ 2048

typedef __attribute__((ext_vector_type(8))) short short8;
typedef __attribute__((ext_vector_type(4))) float floatx4;

// async global->LDS direct copy, 16 bytes per lane
#define GLDS16(g, l)                                                          \
    __builtin_amdgcn_global_load_lds(                                         \
        (const __attribute__((address_space(1))) uint32_t*)(g),               \
        (__attribute__((address_space(3))) uint32_t*)(l), 16, 0, 0)

__device__ inline float b2f(uint16_t u) {
    union { uint32_t i; float f; } x; x.i = (uint32_t)u << 16; return x.f;
}
__device__ inline uint16_t f2b(float f) {
    union { uint32_t i; float f; } x; x.f = f;
    uint32_t r = (x.i + 0x7fff + ((x.i >> 16) & 1)) >> 16;
    return (uint16_t)r;
}

// ---------------- small cast kernel: f32 -> bf16 ----------------
__global__ void cast_f32_bf16(const float* __restrict__ src, uint16_t* __restrict__ dst, int n) {
    int i = blockIdx.x * 256 + threadIdx.x;
    if (i < n) dst[i] = f2b(src[i]);
}

// ---------------- transpose + cast: x [B][C][L] f32 -> xT [B][L][C] bf16 ----------------
__global__ __launch_bounds__(256) void transpose_cast(const float* __restrict__ x, uint16_t* __restrict__ xT) {
    __shared__ float tile[32][33];
    int b = blockIdx.z;
    int l0 = blockIdx.x * 32, c0 = blockIdx.y * 32;
    int tx = threadIdx.x, ty = threadIdx.y;  // blockDim (32, 8)
    const float* xb = x + (size_t)b * C_ * L_;
#pragma unroll
    for (int i = 0; i < 4; i++)
        tile[ty + i * 8][tx] = xb[(size_t)(c0 + ty + i * 8) * L_ + l0 + tx];
    __syncthreads();
    uint16_t* xtb = xT + (size_t)b * L_ * C_;
#pragma unroll
    for (int i = 0; i < 4; i++) {
        int l = l0 + ty + i * 8, c = c0 + tx;
        xtb[(size_t)l * C_ + c] = f2b(tile[tx][ty + i * 8]);
    }
}

// ---------------- qk GEMM (128^2 tile, validated r2 structure) ----------------
__global__ __launch_bounds__(256) void gemm_qk(
    const uint16_t* __restrict__ A, const uint16_t* __restrict__ B, long sB,
    const float* __restrict__ bq, const float* __restrict__ bk,
    uint16_t* __restrict__ Cout, long sC, int K) {

    __shared__ uint4 As4[512];  // 128 x 32 bf16
    __shared__ uint4 Bs4[512];
    uint16_t* As = (uint16_t*)As4;
    uint16_t* Bs = (uint16_t*)Bs4;

    const int b = blockIdx.z;
    const uint16_t* Ab = A;
    const uint16_t* Bb = B + (size_t)b * sB;
    const int m0 = blockIdx.y * 128;
    const int n0 = blockIdx.x * 128;

    const int t = threadIdx.x;
    const int lane = t & 63;
    const int wave = t >> 6;
    const int wm = (wave >> 1) * 64;
    const int wn = (wave & 1) * 64;

    floatx4 acc[4][4] = {};

    const int c0 = t, c1 = t + 256;
    const uint16_t* gA0 = Ab + (size_t)(m0 + (c0 >> 2)) * K + (c0 & 3) * 8;
    const uint16_t* gA1 = Ab + (size_t)(m0 + (c1 >> 2)) * K + (c1 & 3) * 8;
    const uint16_t* gB0 = Bb + (size_t)(n0 + (c0 >> 2)) * K + (c0 & 3) * 8;
    const uint16_t* gB1 = Bb + (size_t)(n0 + (c1 >> 2)) * K + (c1 & 3) * 8;

    for (int k0 = 0; k0 < K; k0 += 32) {
        __syncthreads();
        GLDS16(gA0 + k0, &As4[c0]);
        GLDS16(gA1 + k0, &As4[c1]);
        GLDS16(gB0 + k0, &Bs4[c0]);
        GLDS16(gB1 + k0, &Bs4[c1]);
        __syncthreads();

        const int kg = (lane >> 4) * 8;
        const int rA = wm + (lane & 15);
        const int rB = wn + (lane & 15);
        short8 af[4], bf[4];
#pragma unroll
        for (int i = 0; i < 4; i++) af[i] = *(const short8*)(As + (rA + i * 16) * 32 + kg);
#pragma unroll
        for (int j = 0; j < 4; j++) bf[j] = *(const short8*)(Bs + (rB + j * 16) * 32 + kg);
#pragma unroll
        for (int i = 0; i < 4; i++)
#pragma unroll
            for (int j = 0; j < 4; j++)
                acc[i][j] = __builtin_amdgcn_mfma_f32_16x16x32_bf16(af[i], bf[j], acc[i][j], 0, 0, 0);
    }

    uint16_t* Cb = Cout + (size_t)b * sC;
#pragma unroll
    for (int i = 0; i < 4; i++)
#pragma unroll
        for (int j = 0; j < 4; j++) {
            int mrow = m0 + wm + i * 16 + ((lane >> 4) << 2);
            int ncol = n0 + wn + j * 16 + (lane & 15);
#pragma unroll
            for (int r = 0; r < 4; r++) {
                int mr = mrow + r;
                float val = acc[i][j][r] + (mr < 128 ? bq[mr] : bk[mr - 128]);
                Cb[(size_t)ncol * 256 + mr] = f2b(val);  // transposed store into [L][256]
            }
        }
}

// ============ 256^2 tile, BK=32, 4-slot ring, counted-vmcnt pipelined GEMM ============
// C[m][n] = sum_k A[m][k]*B[n][k], bf16 in, f32 acc.
// Schedule per K-tile kt (slot kt&3):
//   ph1: ds_read af[0..3]+bf[0..3] | issue stage A(kt+3) -> slot (kt-1)&3
//        barrier; lgkmcnt(0); setprio(1); 16 MFMA; setprio(0); barrier
//   ph2: ds_read af[4..7]          | issue stage B(kt+3)
//        barrier; lgkmcnt(0); setprio(1); 16 MFMA; setprio(0)
//   boundary: vmcnt(8/4/0 counted) ; barrier     (guarantees kt+1 landed block-wide)
// T2 swizzle: chunk' = chunk ^ ((row ^ (row>>2)) & 3), applied on BOTH the
// pre-swizzled global source (linear LDS dest, rule 21) and the ds_read addr.
template <int EPI>
__global__ __launch_bounds__(512, 2) void gemm256(
    const uint16_t* __restrict__ A, const uint16_t* __restrict__ B,
    int lda, int ldb, long sA, long sB, const float* __restrict__ bias,
    void* __restrict__ Cout, long sC, int ldc, int K,
    const float* __restrict__ gamma, const float* __restrict__ X) {

    __shared__ uint4 AS[4][1024];  // 4 ring slots x (256 rows x 2 chunk-loads) 16KB
    __shared__ uint4 BS[4][1024];

    const int b = blockIdx.z;
    const uint16_t* Ab = A + (size_t)b * sA;
    const uint16_t* Bb = B + (size_t)b * sB;
    const int m0 = blockIdx.y * 256;
    const int n0 = blockIdx.x * 256;

    const int t = threadIdx.x;          // 512 threads = 8 waves
    const int lane = t & 63;
    const int wid = t >> 6;
    const int wm = (wid >> 2) * 128;    // 2 M-waves
    const int wn = (wid & 3) * 64;      // 4 N-waves

    // ---- stage constants: thread t owns 16B slots t (rows 0-127) and t+512 (rows 128-255)
    const int srow = t >> 2;                                // 0..127
    const int sc = ((t & 3) ^ (srow ^ (srow >> 2))) & 3;    // inverse-swizzled source chunk
    const uint16_t* gA0 = Ab + (size_t)(m0 + srow) * lda + sc * 8;
    const uint16_t* gA1 = Ab + (size_t)(m0 + srow + 128) * lda + sc * 8;
    const uint16_t* gB0 = Bb + (size_t)(n0 + srow) * ldb + sc * 8;
    const uint16_t* gB1 = Bb + (size_t)(n0 + srow + 128) * ldb + sc * 8;

    // ---- ds_read constants (halfword offsets); row bits0-2 == lane bits0-2
    const int rsw = ((lane >> 4) ^ (lane ^ (lane >> 2))) & 3;   // swizzled chunk
    const int aoff = (wm + (lane & 15)) * 32 + rsw * 8;
    const int boff = (wn + (lane & 15)) * 32 + rsw * 8;

    floatx4 acc[8][4] = {};
    const int nt = K >> 5;

#define STA(slot, k0) do { GLDS16(gA0 + (k0), &AS[slot][t]); GLDS16(gA1 + (k0), &AS[slot][t + 512]); } while (0)
#define STB(slot, k0) do { GLDS16(gB0 + (k0), &BS[slot][t]); GLDS16(gB1 + (k0), &BS[slot][t + 512]); } while (0)

    // ---- prologue: stage tiles 0,1,2; wait tile 0 landed (leave 1,2 in flight)
    STA(0, 0); STB(0, 0);
    if (nt > 1) { STA(1, 32); STB(1, 32); }
    if (nt > 2) { STA(2, 64); STB(2, 64); }
    if (nt > 2)      asm volatile("s_waitcnt vmcnt(8)" ::: "memory");
    else if (nt > 1) asm volatile("s_waitcnt vmcnt(4)" ::: "memory");
    else             asm volatile("s_waitcnt vmcnt(0)" ::: "memory");
    __builtin_amdgcn_s_barrier();
    __builtin_amdgcn_sched_barrier(0);

    for (int kt = 0; kt < nt; kt++) {
        const int slot = kt & 3;
        const uint16_t* Ap = (const uint16_t*)AS[slot];
        const uint16_t* Bp = (const uint16_t*)BS[slot];
        const int k3 = (kt + 3) * 32;
        const bool st = (kt + 3) < nt;

        // ---- phase 1 ----
        short8 af[4], bf[4];
#pragma unroll
        for (int i = 0; i < 4; i++) af[i] = *(const short8*)(Ap + aoff + i * 512);
#pragma unroll
        for (int j = 0; j < 4; j++) bf[j] = *(const short8*)(Bp + boff + j * 512);
        if (st) STA((kt + 3) & 3, k3);
        __builtin_amdgcn_s_barrier();
        asm volatile("s_waitcnt lgkmcnt(0)" ::: "memory");
        __builtin_amdgcn_sched_barrier(0);
        __builtin_amdgcn_s_setprio(1);
#pragma unroll
        for (int i = 0; i < 4; i++)
#pragma unroll
            for (int j = 0; j < 4; j++)
                acc[i][j] = __builtin_amdgcn_mfma_f32_16x16x32_bf16(af[i], bf[j], acc[i][j], 0, 0, 0);
        __builtin_amdgcn_s_setprio(0);
        __builtin_amdgcn_s_barrier();
        __builtin_amdgcn_sched_barrier(0);

        // ---- phase 2 ----
        short8 ag[4];
#pragma unroll
        for (int i = 0; i < 4; i++) ag[i] = *(const short8*)(Ap + aoff + (i + 4) * 512);
        if (st) STB((kt + 3) & 3, k3);
        __builtin_amdgcn_s_barrier();
        asm volatile("s_waitcnt lgkmcnt(0)" ::: "memory");
        __builtin_amdgcn_sched_barrier(0);
        __builtin_amdgcn_s_setprio(1);
#pragma unroll
        for (int i = 0; i < 4; i++)
#pragma unroll
            for (int j = 0; j < 4; j++)
                acc[i + 4][j] = __builtin_amdgcn_mfma_f32_16x16x32_bf16(ag[i], bf[j], acc[i + 4][j], 0, 0, 0);
        __builtin_amdgcn_s_setprio(0);

        // ---- K-tile boundary: counted drain guarantees kt+1 landed everywhere
        if (kt + 1 < nt) {
            const int ahead = nt - 2 - kt;  // tiles beyond kt+1 possibly in flight
            if (ahead >= 2)      asm volatile("s_waitcnt vmcnt(8)" ::: "memory");
            else if (ahead == 1) asm volatile("s_waitcnt vmcnt(4)" ::: "memory");
            else                 asm volatile("s_waitcnt vmcnt(0)" ::: "memory");
            __builtin_amdgcn_s_barrier();
            __builtin_amdgcn_sched_barrier(0);
        }
    }
#undef STA
#undef STB

    if (EPI == 0 || EPI == 2) {
        uint16_t* Cb = (uint16_t*)Cout + (size_t)b * sC;
#pragma unroll
        for (int mi = 0; mi < 8; mi++)
#pragma unroll
            for (int nj = 0; nj < 4; nj++) {
                int mrow = m0 + wm + mi * 16 + ((lane >> 4) << 2);
                int ncol = n0 + wn + nj * 16 + (lane & 15);
#pragma unroll
                for (int r = 0; r < 4; r++) {
                    float val = acc[mi][nj][r];
                    if (EPI == 0) val += bias[mrow + r];
                    Cb[(size_t)(mrow + r) * ldc + ncol] = f2b(val);
                }
            }
    } else {  // EPI == 3
        float g = gamma[0];
        float* Ob = (float*)Cout + (size_t)b * sC;
        const float* Xb = X + (size_t)b * sC;
#pragma unroll
        for (int mi = 0; mi < 8; mi++)
#pragma unroll
            for (int nj = 0; nj < 4; nj++) {
                int mrow = m0 + wm + mi * 16 + ((lane >> 4) << 2);
                int ncol = n0 + wn + nj * 16 + (lane & 15);
#pragma unroll
                for (int r = 0; r < 4; r++) {
                    size_t idx = (size_t)(mrow + r) * ldc + ncol;
                    Ob[idx] = g * acc[mi][nj][r] + Xb[idx];
                }
            }
    }
}

// ---------------- row softmax, in-place bf16, one block per row ----------------
__global__ __launch_bounds__(256) void softmax_rows(uint16_t* __restrict__ att) {
    const int i = blockIdx.x, b = blockIdx.y;
    uint16_t* row = att + ((size_t)b * L_ + i) * L_;
    const int t = threadIdx.x;
    short8 v = *(const short8*)(row + t * 8);
    float f[8];
    float m = -1e30f;
#pragma unroll
    for (int e = 0; e < 8; e++) { f[e] = b2f((uint16_t)v[e]); m = fmaxf(m, f[e]); }
#pragma unroll
    for (int off = 32; off >= 1; off >>= 1) m = fmaxf(m, __shfl_xor(m, off));
    __shared__ float redm[4], reds[4];
    const int wave = t >> 6;
    if ((t & 63) == 0) redm[wave] = m;
    __syncthreads();
    m = fmaxf(fmaxf(redm[0], redm[1]), fmaxf(redm[2], redm[3]));
    float s = 0.f;
#pragma unroll
    for (int e = 0; e < 8; e++) { f[e] = __expf(f[e] - m); s += f[e]; }
#pragma unroll
    for (int off = 32; off >= 1; off >>= 1) s += __shfl_xor(s, off);
    if ((t & 63) == 0) reds[wave] = s;
    __syncthreads();
    s = reds[0] + reds[1] + reds[2] + reds[3];
    float inv = 1.0f / s;
    short8 o;
#pragma unroll
    for (int e = 0; e < 8; e++) o[e] = (short)f2b(f[e] * inv);
    *(short8*)(row + t * 8) = o;
}

// ---------------- workspace layout (bytes), total 145,227,776 ----------------
#define OFF_XT   0ull           // 33,554,432  xT  [B][L][C] bf16
#define OFF_QK   33554432ull    //  8,388,608  qk  [B][L][256] bf16
#define OFF_V    41943040ull    // 33,554,432  v   [B][C][L] bf16
#define OFF_ATT  75497472ull    // 67,108,864  att [B][L][L] bf16
#define OFF_WQK  142606336ull   //    524,288  Wqk [256][1024] bf16
#define OFF_WV   143130624ull   //  2,097,152  Wv  [1024][1024] bf16

extern "C" void kernel_launch(void* const* d_in, const int* in_sizes, int n_in,
                              void* d_out, int out_size, void* d_ws, size_t ws_size,
                              hipStream_t stream) {
    const float* x  = (const float*)d_in[0];
    const float* Wq = (const float*)d_in[1];
    const float* bq = (const float*)d_in[2];
    const float* Wk = (const float*)d_in[3];
    const float* bk = (const float*)d_in[4];
    const float* Wv = (const float*)d_in[5];
    const float* bv = (const float*)d_in[6];
    const float* gamma = (const float*)d_in[7];
    float* out = (float*)d_out;
    char* ws = (char*)d_ws;

    uint16_t* xT   = (uint16_t*)(ws + OFF_XT);
    uint16_t* qk   = (uint16_t*)(ws + OFF_QK);
    uint16_t* v    = (uint16_t*)(ws + OFF_V);
    uint16_t* att  = (uint16_t*)(ws + OFF_ATT);
    uint16_t* Wqkb = (uint16_t*)(ws + OFF_WQK);
    uint16_t* Wvb  = (uint16_t*)(ws + OFF_WV);

    // 1. weight casts (Wq into rows 0-127, Wk into rows 128-255 of Wqk)
    cast_f32_bf16<<<dim3((D_ * C_ + 255) / 256), 256, 0, stream>>>(Wq, Wqkb, D_ * C_);
    cast_f32_bf16<<<dim3((D_ * C_ + 255) / 256), 256, 0, stream>>>(Wk, Wqkb + D_ * C_, D_ * C_);
    cast_f32_bf16<<<dim3((C_ * C_ + 255) / 256), 256, 0, stream>>>(Wv, Wvb, C_ * C_);

    // 2. x transpose+cast: [B][C][L] f32 -> [B][L][C] bf16
    transpose_cast<<<dim3(L_ / 32, C_ / 32, B_), dim3(32, 8), 0, stream>>>(x, xT);

    // 3. q,k in one dispatch: qk[b][l][0:128]=q, [128:256]=k (transposed store)
    gemm_qk<<<dim3(L_ / 128, 2, B_), 256, 0, stream>>>(
        Wqkb, xT, (long)L_ * C_, bq, bk, qk, (long)L_ * 256, C_);

    // 4. v = Wv*x (+bv), stored [B][C][L]
    gemm256<0><<<dim3(L_ / 256, C_ / 256, B_), 512, 0, stream>>>(
        Wvb, xT, C_, C_, 0, (long)L_ * C_, bv, v, (long)C_ * L_, L_, C_, nullptr, nullptr);

    // 5. energy[b][i][j] = sum_d q[b][i][d]*k[b][j][d] -> bf16 att
    gemm256<2><<<dim3(L_ / 256, L_ / 256, B_), 512, 0, stream>>>(
        qk, qk + 128, 256, 256, (long)L_ * 256, (long)L_ * 256, nullptr,
        att, (long)L_ * L_, L_, D_, nullptr, nullptr);

    // 6. softmax rows, in place
    softmax_rows<<<dim3(L_, B_), 256, 0, stream>>>(att);

    // 7. out[b][c][i] = gamma * sum_j v[b][c][j]*att[b][i][j] + x[b][c][i]
    gemm256<3><<<dim3(L_ / 256, C_ / 256, B_), 512, 0, stream>>>(
        v, att, L_, L_, (long)C_ * L_, (long)L_ * L_, nullptr,
        out, (long)C_ * L_, L_, L_, gamma, x);
}